// Round 5
// baseline (1394.054 us; speedup 1.0000x reference)
//
#include <hip/hip_runtime.h>

// Encoder: D=4, L=16, C=64, H=W=128.
// Math: softmax_j(A_i+B_j+ba)==softmax_j(B_j) (Q/Wq/bq/ba/bk drop out);
// attn identical for all frames i; B = conv5(h,Weff) done as GEMM into 25
// tap planes T + shift-add.
// Round 4: f1 LDS stride 128->136 u16 (power-of-2 row stride defeats the
// XOR swizzle: 256B rows start at bank 0 every row -> 5M conflicts; 272B
// rows rotate banks by 4/row like the proven stride-72 h layout). Initial
// x copy eliminated (layer-0 kernels read x_in directly).

#define HW 16384
#define CHW 1048576
#define LCHW 16777216

typedef unsigned short u16;
typedef __attribute__((ext_vector_type(8))) short bf16x8;
typedef __attribute__((ext_vector_type(4))) float f32x4;

static __device__ __forceinline__ u16 f2bf(float f) {
  union { float f; unsigned int u; } v; v.f = f;
  unsigned int r = v.u + 0x7fffu + ((v.u >> 16) & 1u);
  return (u16)(r >> 16);
}
static __device__ __forceinline__ float bf2f(u16 h) {
  union { unsigned int u; float f; } v; v.u = ((unsigned int)h) << 16;
  return v.f;
}
static __device__ __forceinline__ void ln_from_acc(const float* acc, int l,
                                                   float& mu, float& r) {
  const float invN = 1.f / 1048576.f;
  float s = acc[2 * l], q = acc[2 * l + 1];
  mu = s * invN;
  r = rsqrtf(q * invN - mu * mu + 1e-5f);
}

// ---- precompute bf16 MFMA fragment packs (layout identical for A/B use):
// pack[((t0*KT+kt)*64+lane)*8+j] = W[m=t0*16+(lane&15)][k=kt*32+(lane>>4)*8+j]
__global__ __launch_bounds__(256) void prep_kernel(
    const float* __restrict__ Wa, const float* __restrict__ Wk,
    const float* __restrict__ Wv, const float* __restrict__ W1,
    const float* __restrict__ W2, u16* __restrict__ w1pk,
    u16* __restrict__ w2pk, u16* __restrict__ wvpk, u16* __restrict__ wepk) {
  int d = blockIdx.x, t = threadIdx.x;
  const float* WaK = Wa + ((size_t)d * 128 + 64) * 25;
  const float* Wkd = Wk + d * 4096;
  for (int idx = t; idx < 2048; idx += 256) {  // Weff: m=tap(32), k=ci(64)
    int frag = idx >> 9, lane = (idx >> 3) & 63, j = idx & 7;
    int mt = frag >> 1, kt = frag & 1;
    int tap = mt * 16 + (lane & 15);
    int ci = kt * 32 + (lane >> 4) * 8 + j;
    float s = 0.f;
    if (tap < 25)
      for (int co = 0; co < 64; ++co)
        s = fmaf(WaK[co * 25 + tap], Wkd[co * 64 + ci], s);
    wepk[d * 2048 + idx] = f2bf(s);
  }
  const float* Wvd = Wv + d * 4096;
  for (int idx = t; idx < 4096; idx += 256) {  // Wv: m=co(64), k=ci(64)
    int frag = idx >> 9, lane = (idx >> 3) & 63, j = idx & 7;
    int mt = frag >> 1, kt = frag & 1;
    int co = mt * 16 + (lane & 15);
    int ci = kt * 32 + (lane >> 4) * 8 + j;
    wvpk[d * 4096 + idx] = f2bf(Wvd[co * 64 + ci]);
  }
  const float* W1d = W1 + d * 8192;
  for (int idx = t; idx < 8192; idx += 256) {  // W1: m=o(128), k=ci(64)
    int frag = idx >> 9, lane = (idx >> 3) & 63, j = idx & 7;
    int mt = frag >> 1, kt = frag & 1;
    int o = mt * 16 + (lane & 15);
    int ci = kt * 32 + (lane >> 4) * 8 + j;
    w1pk[d * 8192 + idx] = f2bf(W1d[o * 64 + ci]);
  }
  const float* W2d = W2 + d * 8192;
  for (int idx = t; idx < 8192; idx += 256) {  // W2: m=c(64), k=o(128)
    int frag = idx >> 9, lane = (idx >> 3) & 63, j = idx & 7;
    int mt2 = frag >> 2, kt2 = frag & 3;
    int c = mt2 * 16 + (lane & 15);
    int o = kt2 * 32 + (lane >> 4) * 8 + j;
    w2pk[d * 8192 + idx] = f2bf(W2d[c * 128 + o]);
  }
}

// ---- per-frame stats of x_in (no copy) ----
__global__ __launch_bounds__(256) void stats_kernel(
    const float* __restrict__ xin, float* __restrict__ acc) {
  int tid = threadIdx.x;
  size_t base = (size_t)blockIdx.x * 4096;
  const float4* in4 = (const float4*)(xin + base);
  float s = 0.f, q = 0.f;
#pragma unroll
  for (int k = 0; k < 4; ++k) {
    float4 v = in4[k * 256 + tid];
    s += v.x + v.y + v.z + v.w;
    q = fmaf(v.x, v.x, q); q = fmaf(v.y, v.y, q);
    q = fmaf(v.z, v.z, q); q = fmaf(v.w, v.w, q);
  }
#pragma unroll
  for (int off = 32; off > 0; off >>= 1) {
    s += __shfl_down(s, off); q += __shfl_down(q, off);
  }
  __shared__ float ls[4], lq[4];
  int wave = tid >> 6;
  if ((tid & 63) == 0) { ls[wave] = s; lq[wave] = q; }
  __syncthreads();
  if (tid == 0) {
    int frame = blockIdx.x >> 8;
    atomicAdd(&acc[frame * 2], ls[0] + ls[1] + ls[2] + ls[3]);
    atomicAdd(&acc[frame * 2 + 1], lq[0] + lq[1] + lq[2] + lq[3]);
  }
}

// ---- fused LN1 + V GEMM + T GEMM, transposed outputs D[px][*] ----
__global__ __launch_bounds__(256) void vb_kernel(
    const float* __restrict__ x, const float* __restrict__ g,
    const float* __restrict__ bln, const u16* __restrict__ wvp_g,
    const float* __restrict__ bv, const u16* __restrict__ wep_g,
    const float* __restrict__ accA, float* __restrict__ accBz,
    u16* __restrict__ Vb, float* __restrict__ T) {
  __shared__ __align__(16) char lds[30720];
  u16* hb = (u16*)lds;
  u16* wvl = (u16*)(lds + 18432);
  u16* wel = (u16*)(lds + 26624);
  int tid = threadIdx.x;
  int l = blockIdx.y;
  int p0 = blockIdx.x << 7;
  if (blockIdx.x == 0 && blockIdx.y == 0 && tid < 32) accBz[tid] = 0.f;
  float mu, r;
  ln_from_acc(accA, l, mu, r);

  const uint4* wv4 = (const uint4*)wvp_g;
  const uint4* we4 = (const uint4*)wep_g;
  ((uint4*)wvl)[tid] = wv4[tid];
  ((uint4*)wvl)[tid + 256] = wv4[tid + 256];
  ((uint4*)wel)[tid] = we4[tid];

#pragma unroll
  for (int it = 0; it < 2; ++it) {
    int pq = tid & 31, cg = (tid >> 5) + it * 8;
    int px = pq * 4, c0 = cg * 4;
    float vv[4][4];
#pragma unroll
    for (int i = 0; i < 4; ++i) {
      int c = c0 + i;
      size_t gi = (((size_t)l * 64 + c) << 14) + p0 + px;
      int li = (c << 14) + p0 + px;
      float4 xv = *(const float4*)(x + gi);
      float4 gv = *(const float4*)(g + li);
      float4 bb = *(const float4*)(bln + li);
      vv[i][0] = (xv.x - mu) * r * gv.x + bb.x;
      vv[i][1] = (xv.y - mu) * r * gv.y + bb.y;
      vv[i][2] = (xv.z - mu) * r * gv.z + bb.z;
      vv[i][3] = (xv.w - mu) * r * gv.w + bb.w;
    }
#pragma unroll
    for (int k = 0; k < 4; ++k) {
      int row = px + k;
      int col = c0 ^ ((row & 7) * 8);
      ushort4 hv;
      hv.x = f2bf(vv[0][k]); hv.y = f2bf(vv[1][k]);
      hv.z = f2bf(vv[2][k]); hv.w = f2bf(vv[3][k]);
      *(ushort4*)(hb + row * 72 + col) = hv;
    }
  }
  __syncthreads();

  int wv = tid >> 6, lane = tid & 63;
  int ln15 = lane & 15, quad = lane >> 4;

  bf16x8 ah[2][2];
#pragma unroll
  for (int mt = 0; mt < 2; ++mt) {
    int px = (wv * 2 + mt) * 16 + ln15;
    int swz = (px & 7) * 8;
#pragma unroll
    for (int kt = 0; kt < 2; ++kt)
      ah[mt][kt] = *(const bf16x8*)(hb + px * 72 + ((kt * 32 + quad * 8) ^ swz));
  }
  bf16x8 bwv[4][2], bwe[2][2];
#pragma unroll
  for (int nt = 0; nt < 4; ++nt)
#pragma unroll
    for (int kt = 0; kt < 2; ++kt)
      bwv[nt][kt] = *(const bf16x8*)(wvl + ((nt * 2 + kt) * 64 + lane) * 8);
#pragma unroll
  for (int nt = 0; nt < 2; ++nt)
#pragma unroll
    for (int kt = 0; kt < 2; ++kt)
      bwe[nt][kt] = *(const bf16x8*)(wel + ((nt * 2 + kt) * 64 + lane) * 8);

  f32x4 accV[2][4], accT[2][2];
#pragma unroll
  for (int mt = 0; mt < 2; ++mt) {
#pragma unroll
    for (int nt = 0; nt < 4; ++nt) accV[mt][nt] = (f32x4){0.f, 0.f, 0.f, 0.f};
#pragma unroll
    for (int nt = 0; nt < 2; ++nt) accT[mt][nt] = (f32x4){0.f, 0.f, 0.f, 0.f};
  }
#pragma unroll
  for (int mt = 0; mt < 2; ++mt)
#pragma unroll
    for (int kt = 0; kt < 2; ++kt) {
#pragma unroll
      for (int nt = 0; nt < 4; ++nt)
        accV[mt][nt] = __builtin_amdgcn_mfma_f32_16x16x32_bf16(
            ah[mt][kt], bwv[nt][kt], accV[mt][nt], 0, 0, 0);
#pragma unroll
      for (int nt = 0; nt < 2; ++nt)
        accT[mt][nt] = __builtin_amdgcn_mfma_f32_16x16x32_bf16(
            ah[mt][kt], bwe[nt][kt], accT[mt][nt], 0, 0, 0);
    }

#pragma unroll
  for (int mt = 0; mt < 2; ++mt) {
    int pxb = p0 + (wv * 2 + mt) * 16 + quad * 4;
#pragma unroll
    for (int nt = 0; nt < 4; ++nt) {
      int c = nt * 16 + ln15;
      float bvc = bv[c];
      ushort4 o;
      o.x = f2bf(accV[mt][nt][0] + bvc);
      o.y = f2bf(accV[mt][nt][1] + bvc);
      o.z = f2bf(accV[mt][nt][2] + bvc);
      o.w = f2bf(accV[mt][nt][3] + bvc);
      *(ushort4*)(Vb + (((size_t)l * 64 + c) << 14) + pxb) = o;
    }
#pragma unroll
    for (int nt = 0; nt < 2; ++nt) {
      int tap = nt * 16 + ln15;
      if (tap < 25) {
        float4 o = {accT[mt][nt][0], accT[mt][nt][1], accT[mt][nt][2],
                    accT[mt][nt][3]};
        *(float4*)(T + (((size_t)l * 25 + tap) << 14) + pxb) = o;
      }
    }
  }
}

// ---- B[l][p] = sum_tap T[l][tap][p + off(tap)] ----
__global__ __launch_bounds__(256) void bconv_kernel(
    const float* __restrict__ T, float* __restrict__ B) {
  int gid = blockIdx.x * 256 + threadIdx.x;
  int l = gid >> 14, p = gid & 16383;
  int y = p >> 7, xx = p & 127;
  float s = 0.f;
#pragma unroll
  for (int dy = 0; dy < 5; ++dy) {
    int yy = y + dy - 2;
    if (yy < 0 || yy > 127) continue;
#pragma unroll
    for (int dx = 0; dx < 5; ++dx) {
      int xc = xx + dx - 2;
      if (xc < 0 || xc > 127) continue;
      s += T[(((size_t)l * 25 + dy * 5 + dx) << 14) + (yy << 7) + xc];
    }
  }
  B[gid] = s;
}

// ---- fused: softmax over j, attnc, broadcast x+=, per-frame stats ----
__global__ __launch_bounds__(256) void attnc_update_kernel(
    const float* __restrict__ xsrc, float* __restrict__ xdst,
    const u16* __restrict__ Vb, const float* __restrict__ B,
    float* __restrict__ accB, float* __restrict__ accAz) {
  int tid = threadIdx.x;
  if (blockIdx.x == 0 && tid < 32) accAz[tid] = 0.f;
  int gid = blockIdx.x * 256 + tid;
  int c = gid >> 12;
  int p4 = (gid & 4095) << 2;
  float4 bj[16];
  float4 m = {-1e30f, -1e30f, -1e30f, -1e30f};
#pragma unroll
  for (int j = 0; j < 16; ++j) {
    bj[j] = *(const float4*)(B + (j << 14) + p4);
    m.x = fmaxf(m.x, bj[j].x); m.y = fmaxf(m.y, bj[j].y);
    m.z = fmaxf(m.z, bj[j].z); m.w = fmaxf(m.w, bj[j].w);
  }
  float4 sum = {0.f, 0.f, 0.f, 0.f};
#pragma unroll
  for (int j = 0; j < 16; ++j) {
    bj[j].x = __expf(bj[j].x - m.x); bj[j].y = __expf(bj[j].y - m.y);
    bj[j].z = __expf(bj[j].z - m.z); bj[j].w = __expf(bj[j].w - m.w);
    sum.x += bj[j].x; sum.y += bj[j].y; sum.z += bj[j].z; sum.w += bj[j].w;
  }
  float4 a = {0.f, 0.f, 0.f, 0.f};
#pragma unroll
  for (int j = 0; j < 16; ++j) {
    ushort4 v = *(const ushort4*)(Vb + (((size_t)j * 64 + c) << 14) + p4);
    a.x = fmaf(bj[j].x, bf2f(v.x), a.x);
    a.y = fmaf(bj[j].y, bf2f(v.y), a.y);
    a.z = fmaf(bj[j].z, bf2f(v.z), a.z);
    a.w = fmaf(bj[j].w, bf2f(v.w), a.w);
  }
  a.x /= sum.x; a.y /= sum.y; a.z /= sum.z; a.w /= sum.w;
  float sf[16], qf[16];
#pragma unroll
  for (int f = 0; f < 16; ++f) {
    size_t off = ((size_t)f << 20) + ((size_t)c << 14) + p4;
    float4 v = *(const float4*)(xsrc + off);
    v.x += a.x; v.y += a.y; v.z += a.z; v.w += a.w;
    *(float4*)(xdst + off) = v;
    sf[f] = v.x + v.y + v.z + v.w;
    float q = 0.f;
    q = fmaf(v.x, v.x, q); q = fmaf(v.y, v.y, q);
    q = fmaf(v.z, v.z, q); q = fmaf(v.w, v.w, q);
    qf[f] = q;
  }
#pragma unroll
  for (int off = 32; off > 0; off >>= 1) {
#pragma unroll
    for (int f = 0; f < 16; ++f) {
      sf[f] += __shfl_down(sf[f], off);
      qf[f] += __shfl_down(qf[f], off);
    }
  }
  __shared__ float lsq[4][32];
  int wv = tid >> 6;
  if ((tid & 63) == 0) {
#pragma unroll
    for (int f = 0; f < 16; ++f) {
      lsq[wv][2 * f] = sf[f];
      lsq[wv][2 * f + 1] = qf[f];
    }
  }
  __syncthreads();
  if (tid < 32)
    atomicAdd(&accB[tid],
              lsq[0][tid] + lsq[1][tid] + lsq[2][tid] + lsq[3][tid]);
}

// ---- fused LN2 + FFN (MFMA, transposed GEMM2) + residual + stats ----
// LDS: h[128][72] swz (18432) | w1 16KB @18432 ; f1[128][136] swz overlays
// both exactly (34816) ; w2 16KB @34816. 51200 B.
__global__ __launch_bounds__(256) void ffn_kernel(
    float* __restrict__ x, const float* __restrict__ g,
    const float* __restrict__ bln, const u16* __restrict__ w1p_g,
    const float* __restrict__ b1, const u16* __restrict__ w2p_g,
    const float* __restrict__ b2, const float* __restrict__ accB,
    float* __restrict__ accA) {
  __shared__ __align__(16) char lds[51200];
  u16* hb = (u16*)lds;
  u16* w1l = (u16*)(lds + 18432);
  u16* f1 = (u16*)lds;  // stride 136 u16, overlays hb+w1l after GEMM1
  u16* w2l = (u16*)(lds + 34816);

  int tid = threadIdx.x;
  int P0 = blockIdx.x << 7;
  int l = P0 >> 14;
  int p0 = P0 & 16383;
  float mu, r;
  ln_from_acc(accB, l, mu, r);

  const uint4* w1g4 = (const uint4*)w1p_g;
  const uint4* w2g4 = (const uint4*)w2p_g;
  for (int i = tid; i < 1024; i += 256) ((uint4*)w1l)[i] = w1g4[i];
  for (int i = tid; i < 1024; i += 256) ((uint4*)w2l)[i] = w2g4[i];

#pragma unroll
  for (int it = 0; it < 2; ++it) {
    int pq = tid & 31, cg = (tid >> 5) + it * 8;
    int px = pq * 4, c0 = cg * 4;
    float vv[4][4];
#pragma unroll
    for (int i = 0; i < 4; ++i) {
      int c = c0 + i;
      size_t gi = (((size_t)l * 64 + c) << 14) + p0 + px;
      int li = (c << 14) + p0 + px;
      float4 xv = *(const float4*)(x + gi);
      float4 gv = *(const float4*)(g + li);
      float4 bb = *(const float4*)(bln + li);
      vv[i][0] = (xv.x - mu) * r * gv.x + bb.x;
      vv[i][1] = (xv.y - mu) * r * gv.y + bb.y;
      vv[i][2] = (xv.z - mu) * r * gv.z + bb.z;
      vv[i][3] = (xv.w - mu) * r * gv.w + bb.w;
    }
#pragma unroll
    for (int k = 0; k < 4; ++k) {
      int row = px + k;
      int col = c0 ^ ((row & 7) * 8);
      ushort4 hv;
      hv.x = f2bf(vv[0][k]); hv.y = f2bf(vv[1][k]);
      hv.z = f2bf(vv[2][k]); hv.w = f2bf(vv[3][k]);
      *(ushort4*)(hb + row * 72 + col) = hv;
    }
  }
  __syncthreads();

  int wv = tid >> 6, lane = tid & 63;
  int ln15 = lane & 15, quad = lane >> 4;

  // GEMM1: D[o=128][px], A=W1 pack, B=h
  bf16x8 a1[8][2];
#pragma unroll
  for (int mt = 0; mt < 8; ++mt)
#pragma unroll
    for (int kt = 0; kt < 2; ++kt)
      a1[mt][kt] = *(const bf16x8*)(w1l + ((mt * 2 + kt) * 64 + lane) * 8);
  bf16x8 bh[2][2];
#pragma unroll
  for (int nt = 0; nt < 2; ++nt) {
    int px = (wv * 2 + nt) * 16 + ln15;
    int swz = (px & 7) * 8;
#pragma unroll
    for (int kt = 0; kt < 2; ++kt)
      bh[nt][kt] = *(const bf16x8*)(hb + px * 72 + ((kt * 32 + quad * 8) ^ swz));
  }
  f32x4 acc1[2][8];
#pragma unroll
  for (int nt = 0; nt < 2; ++nt)
#pragma unroll
    for (int mt = 0; mt < 8; ++mt) acc1[nt][mt] = (f32x4){0.f, 0.f, 0.f, 0.f};
#pragma unroll
  for (int mt = 0; mt < 8; ++mt)
#pragma unroll
    for (int kt = 0; kt < 2; ++kt)
#pragma unroll
      for (int nt = 0; nt < 2; ++nt)
        acc1[nt][mt] = __builtin_amdgcn_mfma_f32_16x16x32_bf16(
            a1[mt][kt], bh[nt][kt], acc1[nt][mt], 0, 0, 0);
  __syncthreads();

  // bias+leaky -> f1[px][o], stride 136, swizzled ushort4 writes
#pragma unroll
  for (int nt = 0; nt < 2; ++nt) {
    int px = (wv * 2 + nt) * 16 + ln15;
    int swz = (px & 7) * 8;
#pragma unroll
    for (int mt = 0; mt < 8; ++mt) {
      int o0 = mt * 16 + quad * 4;
      float4 b1v = *(const float4*)(b1 + o0);
      float fv[4];
#pragma unroll
      for (int rj = 0; rj < 4; ++rj) {
        float f = acc1[nt][mt][rj] + ((const float*)&b1v)[rj];
        fv[rj] = fmaxf(f, 0.01f * f);
      }
      int col = ((o0 & ~7) ^ swz) + (o0 & 7);
      ushort4 ov;
      ov.x = f2bf(fv[0]); ov.y = f2bf(fv[1]);
      ov.z = f2bf(fv[2]); ov.w = f2bf(fv[3]);
      *(ushort4*)(f1 + px * 136 + col) = ov;
    }
  }
  __syncthreads();

  // GEMM2 transposed: D[px][c], A=f1 rows, B=W2 pack
  bf16x8 a2[2][4];
#pragma unroll
  for (int mt = 0; mt < 2; ++mt) {
    int px = (wv * 2 + mt) * 16 + ln15;
    int swz = (px & 7) * 8;
#pragma unroll
    for (int kt = 0; kt < 4; ++kt)
      a2[mt][kt] =
          *(const bf16x8*)(f1 + px * 136 + ((kt * 32 + quad * 8) ^ swz));
  }
  bf16x8 b2f[4][4];
#pragma unroll
  for (int nt = 0; nt < 4; ++nt)
#pragma unroll
    for (int kt = 0; kt < 4; ++kt)
      b2f[nt][kt] = *(const bf16x8*)(w2l + ((nt * 4 + kt) * 64 + lane) * 8);
  f32x4 acc2[2][4];
#pragma unroll
  for (int mt = 0; mt < 2; ++mt)
#pragma unroll
    for (int nt = 0; nt < 4; ++nt) acc2[mt][nt] = (f32x4){0.f, 0.f, 0.f, 0.f};
#pragma unroll
  for (int mt = 0; mt < 2; ++mt)
#pragma unroll
    for (int kt = 0; kt < 4; ++kt)
#pragma unroll
      for (int nt = 0; nt < 4; ++nt)
        acc2[mt][nt] = __builtin_amdgcn_mfma_f32_16x16x32_bf16(
            a2[mt][kt], b2f[nt][kt], acc2[mt][nt], 0, 0, 0);

  float s = 0.f, q = 0.f;
#pragma unroll
  for (int mt = 0; mt < 2; ++mt) {
    int pxb = p0 + (wv * 2 + mt) * 16 + quad * 4;
#pragma unroll
    for (int nt = 0; nt < 4; ++nt) {
      int c = nt * 16 + ln15;
      float b2c = b2[c];
      float4* xp = (float4*)(x + (((size_t)l * 64 + c) << 14) + pxb);
      float4 v = *xp;
      v.x += acc2[mt][nt][0] + b2c;
      v.y += acc2[mt][nt][1] + b2c;
      v.z += acc2[mt][nt][2] + b2c;
      v.w += acc2[mt][nt][3] + b2c;
      *xp = v;
      s += v.x + v.y + v.z + v.w;
      q = fmaf(v.x, v.x, q); q = fmaf(v.y, v.y, q);
      q = fmaf(v.z, v.z, q); q = fmaf(v.w, v.w, q);
    }
  }
#pragma unroll
  for (int off = 32; off > 0; off >>= 1) {
    s += __shfl_down(s, off); q += __shfl_down(q, off);
  }
  if (lane == 0) {
    atomicAdd(&accA[l * 2], s);
    atomicAdd(&accA[l * 2 + 1], q);
  }
}

extern "C" void kernel_launch(void* const* d_in, const int* in_sizes, int n_in,
                              void* d_out, int out_size, void* d_ws,
                              size_t ws_size, hipStream_t stream) {
  const float* x_in = (const float*)d_in[0];
  const float* ln1_g = (const float*)d_in[1];
  const float* ln1_b = (const float*)d_in[2];
  const float* Wk = (const float*)d_in[5];
  const float* Wv = (const float*)d_in[7];
  const float* bv = (const float*)d_in[8];
  const float* Wa = (const float*)d_in[9];
  const float* ln2_g = (const float*)d_in[11];
  const float* ln2_b = (const float*)d_in[12];
  const float* W1 = (const float*)d_in[13];
  const float* b1 = (const float*)d_in[14];
  const float* W2 = (const float*)d_in[15];
  const float* b2 = (const float*)d_in[16];

  float* xbuf = (float*)d_out;
  float* ws = (float*)d_ws;
  u16* Vb = (u16*)ws;                  // [0, 8388608) fl
  float* T = ws + 8388608;             // 6553600
  float* Bbuf = ws + 14942208;         // 262144
  u16* w1pk = (u16*)(ws + 15204352);   // 32768 u16
  u16* w2pk = (u16*)(ws + 15220736);   // 32768 u16
  u16* wvpk = (u16*)(ws + 15237120);   // 16384 u16
  u16* wepk = (u16*)(ws + 15245312);   // 8192 u16
  float* accA = ws + 15249408;         // 32
  float* accB = ws + 15249440;         // 32

  hipMemsetAsync(accA, 0, 256, stream);  // accA + accB
  prep_kernel<<<4, 256, 0, stream>>>(Wa, Wk, Wv, W1, W2, w1pk, w2pk, wvpk,
                                     wepk);
  stats_kernel<<<4096, 256, 0, stream>>>(x_in, accA);

  for (int d = 0; d < 4; ++d) {
    const float* xsrc = (d == 0) ? x_in : xbuf;
    vb_kernel<<<dim3(128, 16), 256, 0, stream>>>(
        xsrc, ln1_g + (size_t)d * CHW, ln1_b + (size_t)d * CHW,
        wvpk + d * 4096, bv + d * 64, wepk + d * 2048, accA, accB, Vb, T);
    bconv_kernel<<<1024, 256, 0, stream>>>(T, Bbuf);
    attnc_update_kernel<<<1024, 256, 0, stream>>>(xsrc, xbuf, Vb, Bbuf, accB,
                                                  accA);
    ffn_kernel<<<2048, 256, 0, stream>>>(
        xbuf, ln2_g + (size_t)d * CHW, ln2_b + (size_t)d * CHW,
        w1pk + d * 8192, b1 + d * 128, w2pk + d * 8192, b2 + d * 64, accB,
        accA);
  }
}